// Round 1
// baseline (257.637 us; speedup 1.0000x reference)
//
#include <hip/hip_runtime.h>
#include <stdint.h>
#include <math.h>

#define BS    2
#define RAYS  514
#define NS    64
#define LSEQ  512
#define NF    257
#define HIDN  64

#define TWO_PI_F 6.28318530717958647692f

__device__ __forceinline__ uint32_t rotl32(uint32_t x, int d){ return (x<<d)|(x>>(32-d)); }

__device__ __forceinline__ void tf_rounds4(uint32_t& x0, uint32_t& x1, int a, int b, int c, int d){
  x0+=x1; x1=rotl32(x1,a); x1^=x0;
  x0+=x1; x1=rotl32(x1,b); x1^=x0;
  x0+=x1; x1=rotl32(x1,c); x1^=x0;
  x0+=x1; x1=rotl32(x1,d); x1^=x0;
}

// Threefry-2x32, 20 rounds, matching jax._src.prng.threefry2x32
__device__ void threefry2x32(uint32_t k0, uint32_t k1, uint32_t x0, uint32_t x1,
                             uint32_t& o0, uint32_t& o1)
{
  const uint32_t ks2 = k0 ^ k1 ^ 0x1BD11BDAu;
  x0 += k0; x1 += k1;
  tf_rounds4(x0,x1,13,15,26,6);   x0+=k1;  x1+=ks2+1u;
  tf_rounds4(x0,x1,17,29,16,24);  x0+=ks2; x1+=k0+2u;
  tf_rounds4(x0,x1,13,15,26,6);   x0+=k0;  x1+=k1+3u;
  tf_rounds4(x0,x1,17,29,16,24);  x0+=k1;  x1+=ks2+4u;
  tf_rounds4(x0,x1,13,15,26,6);   x0+=ks2; x1+=k0+5u;
  o0 = x0; o1 = x1;
}

// Reproduces _ray_directions() for ray r.
// jax.random.key(42) -> threefry key (0, 42).
// Partitionable random_bits (modern JAX default): counter = flat index i as u64
// -> threefry(k, hi=0, lo=i), 32-bit output = out0 ^ out1.
__device__ void ray_dir(int r, float d[3])
{
  if (r >= 512) { d[0]=0.f; d[1]=0.f; d[2] = (r==512) ? 1.0f : -1.0f; return; }
  int i = r >> 4, j = r & 15;
  uint32_t o0, o1;
  threefry2x32(0u, 42u, 0u, (uint32_t)i, o0, o1);
  uint32_t bits = o0 ^ o1;
  float u = __uint_as_float((bits >> 9) | 0x3F800000u) - 1.0f;   // uniform [0,1)
  const float step = TWO_PI_F / 32.0f;                            // linspace delta == 2pi/32
  float a = (float)i * step + step * u;
  float e = acosf(2.0f * ((float)(j+1) * (1.0f/17.0f)) - 1.0f);
  float se = sinf(e);
  d[0] = cosf(a) * se;
  d[1] = sinf(a) * se;
  d[2] = cosf(e);
}

__device__ __forceinline__ float dval(int s){ return ((float)s*(1.0f/63.0f))*7.9f + 0.1f; }

// K1: per-ray MLP + attention weights + tx-delay; emits w*h (64-vec), w, delay.
__global__ __launch_bounds__(64)
void k1_rays(const float* __restrict__ rays_o, const float* __restrict__ position_tx,
             const float* __restrict__ W1, const float* __restrict__ b1,
             const float* __restrict__ w_attn,
             float* __restrict__ wh, float* __restrict__ w_arr, int* __restrict__ delay_arr)
{
  const int br = blockIdx.x;
  const int b = br / RAYS, r = br % RAYS;
  const int lane = threadIdx.x;

  float dir[3]; ray_dir(r, dir);
  const float mn[3] = {-5.f,-5.f,-3.f}, mx[3] = {5.f,5.f,3.f};
  float ro[3], ntx[3];
  #pragma unroll
  for (int c=0;c<3;c++){
    ro[c] = rays_o[b*3+c];
    float t = position_tx[b*3+c];
    ntx[c] = 2.0f*(t - mn[c])/(mx[c]-mn[c]) - 1.0f;
  }
  float w1r[9];
  #pragma unroll
  for (int f=0; f<9; f++) w1r[f] = W1[f*HIDN + lane];
  const float b1r = b1[lane];
  const float war = w_attn[lane];

  float T = 1.0f;
  for (int s=0; s<NS; s++){
    float dv = dval(s);
    float npt[3], dd2 = 0.f;
    #pragma unroll
    for (int c=0;c<3;c++){
      float pt = ro[c] + dir[c]*dv;
      npt[c] = 2.0f*(pt - mn[c])/(mx[c]-mn[c]) - 1.0f;
      // denormalize(ntx - npt), per reference op order
      float ddc = ((ntx[c]-npt[c]) + 1.0f)/2.0f*(mx[c]-mn[c]) + mn[c];
      dd2 += ddc*ddc;
    }
    float h = b1r;
    h += npt[0]*w1r[0] + npt[1]*w1r[1] + npt[2]*w1r[2];
    h += (-dir[0])*w1r[3] + (-dir[1])*w1r[4] + (-dir[2])*w1r[5];
    h += ntx[0]*w1r[6] + ntx[1]*w1r[7] + ntx[2]*w1r[8];
    h = fmaxf(h, 0.0f);

    float av = h * war;
    #pragma unroll
    for (int m=32; m>=1; m>>=1) av += __shfl_xor(av, m, 64);

    // softplus == logaddexp(x, 0)
    float attn = fmaxf(av, 0.f) + log1pf(expf(-fabsf(av)));
    float dist = (s < NS-1) ? (dval(s+1) - dv) : 1e10f;
    float alpha = 1.0f - expf(-attn*dist);
    float wgt = T * alpha;
    T = T * (1.0f - alpha + 1e-6f);

    float idxf = (sqrtf(dd2)*16000.0f)/343.0f;
    float delf = fminf(fmaxf(rintf(idxf), 0.f), 511.f);  // rint = round-half-even, like jnp.round

    size_t base = ((size_t)(b*RAYS + r)*NS + s)*HIDN;
    wh[base + lane] = wgt * h;
    if (lane == 0){
      int o = (b*RAYS + r)*NS + s;
      w_arr[o] = wgt;
      delay_arr[o] = (int)delf;
    }
  }
}

// K2: per (b,s): delay-bucket scatter of w*h (+ w), inclusive prefix over delay,
// then g[l] = (Hcum[l]·W_sig[:,l] + b_sig[l]*Wsum[l]) * mask_tail * path_loss.
__global__ __launch_bounds__(128)
void k2_gather(const float* __restrict__ wh, const float* __restrict__ w_arr,
               const int* __restrict__ delay_arr,
               const float* __restrict__ W_sig, const float* __restrict__ b_sig,
               float* __restrict__ g)
{
  __shared__ float bucket[LSEQ][HIDN+1];   // 512*65*4 = 133,120 B (stride 65 -> conflict-free)
  const int bsid = blockIdx.x;
  const int b = bsid / NS, s = bsid % NS;
  const int tid = threadIdx.x;

  for (int i = tid; i < LSEQ*(HIDN+1); i += 128) (&bucket[0][0])[i] = 0.f;
  __syncthreads();

  if (tid < 64){
    // wave 0: lane t owns column t; ds_add is fire-and-forget (no RMW latency chain)
    for (int r=0; r<RAYS; r++){
      int o = (b*RAYS + r)*NS + s;
      int d = delay_arr[o];
      float v = wh[((size_t)(b*RAYS + r)*NS + s)*HIDN + tid];
      atomicAdd(&bucket[d][tid], v);
    }
  } else if (tid == 64){
    for (int r=0; r<RAYS; r++){
      int o = (b*RAYS + r)*NS + s;
      atomicAdd(&bucket[delay_arr[o]][HIDN], w_arr[o]);
    }
  }
  __syncthreads();

  if (tid <= 64){
    float run = 0.f;
    for (int d2=0; d2<LSEQ; d2++){
      run += bucket[d2][tid];
      bucket[d2][tid] = run;
    }
  }
  __syncthreads();

  float dv = dval(s);
  float shiftf = rintf((16000.0f*dv)/343.0f);
  int shift = (int)shiftf;

  for (int l = tid; l < LSEQ; l += 128){
    float acc = b_sig[l] * bucket[l][HIDN];
    #pragma unroll 16
    for (int j=0; j<HIDN; j++) acc += bucket[l][j] * W_sig[j*LSEQ + l];
    float mt = (((float)(LSEQ-1-l)) - shiftf > 0.f) ? 1.f : 0.f;
    int pli = shift + l;
    if (pli < 4) pli = 5;                       // path_loss[:4] = path_loss[5]
    float ideal = ((float)pli/16000.0f)*343.0f;
    float plv = 1.0f/(ideal + 0.001f);
    g[(b*NS + s)*LSEQ + l] = acc * mt * plv;
  }
}

// K3: per (b,s): 512-pt direct DFT (LDS twiddle table) + fractional-delay phase.
__global__ __launch_bounds__(256)
void k3_dft(const float* __restrict__ g, float* __restrict__ partial)
{
  __shared__ float gs[LSEQ];
  __shared__ float twr[LSEQ];
  __shared__ float twi[LSEQ];
  const int bsid = blockIdx.x;
  const int b = bsid / NS, s = bsid % NS;
  const int tid = threadIdx.x;

  for (int l = tid; l < LSEQ; l += 256){
    gs[l] = g[(b*NS + s)*LSEQ + l];
    float sv, cv;
    sincosf(-(TWO_PI_F/512.0f)*(float)l, &sv, &cv);
    twr[l] = cv; twi[l] = sv;
  }
  __syncthreads();

  float c = (16000.0f*dval(s))/343.0f;   // fractional pts2rx_idx
  for (int k = tid; k < NF; k += 256){
    float re = 0.f, im = 0.f;
    for (int l=0; l<LSEQ; l++){
      int t = (k*l) & (LSEQ-1);
      float gv = gs[l];
      re = fmaf(gv, twr[t], re);
      im = fmaf(gv, twi[t], im);
    }
    float ang = -(TWO_PI_F/512.0f)*((float)k*c);
    float sp, cp; sincosf(ang, &sp, &cp);
    float orr = re*cp - im*sp;
    float oi  = re*sp + im*cp;
    size_t o = ((size_t)(b*NS + s)*NF + k)*2;
    partial[o]   = orr;
    partial[o+1] = oi;
  }
}

// K4: deterministic reduction over s.
__global__ __launch_bounds__(256)
void k4_reduce(const float* __restrict__ partial, float* __restrict__ out)
{
  int idx = blockIdx.x*256 + threadIdx.x;
  if (idx >= BS*NF*2) return;
  int b = idx / (NF*2);
  int rem = idx - b*(NF*2);
  int k = rem >> 1, comp = rem & 1;
  float acc = 0.f;
  for (int s=0; s<NS; s++) acc += partial[((size_t)(b*NS + s)*NF + k)*2 + comp];
  out[(b*NF + k)*2 + comp] = acc;
}

extern "C" void kernel_launch(void* const* d_in, const int* in_sizes, int n_in,
                              void* d_out, int out_size, void* d_ws, size_t ws_size,
                              hipStream_t stream)
{
  const float* rays_o      = (const float*)d_in[0];
  const float* position_tx = (const float*)d_in[1];
  const float* W1          = (const float*)d_in[2];
  const float* b1          = (const float*)d_in[3];
  const float* w_attn      = (const float*)d_in[4];
  const float* W_sig       = (const float*)d_in[5];
  const float* b_sig       = (const float*)d_in[6];
  float* out = (float*)d_out;

  float* ws = (float*)d_ws;
  float* wh        = ws;                                        // BS*RAYS*NS*HIDN = 4,210,688 f32
  float* w_arr     = wh + (size_t)BS*RAYS*NS*HIDN;              // 65,792 f32
  int*   delay_arr = (int*)(w_arr + (size_t)BS*RAYS*NS);        // 65,792 i32
  float* g         = (float*)(delay_arr + (size_t)BS*RAYS*NS);  // 65,536 f32
  float* partial   = g + (size_t)BS*NS*LSEQ;                    // 65,792 f32
  // total ~17.9 MB of d_ws

  k1_rays  <<<BS*RAYS,          64, 0, stream>>>(rays_o, position_tx, W1, b1, w_attn,
                                                 wh, w_arr, delay_arr);
  k2_gather<<<BS*NS,           128, 0, stream>>>(wh, w_arr, delay_arr, W_sig, b_sig, g);
  k3_dft   <<<BS*NS,           256, 0, stream>>>(g, partial);
  k4_reduce<<<(BS*NF*2+255)/256,256, 0, stream>>>(partial, out);
}

// Round 2
// 125.555 us; speedup vs baseline: 2.0520x; 2.0520x over previous
//
#include <hip/hip_runtime.h>
#include <hip/hip_fp16.h>
#include <stdint.h>
#include <math.h>

#define BS    2
#define RAYS  514
#define NS    64
#define LSEQ  512
#define NF    257
#define HIDN  64
#define SPLIT 4
#define JC    16      // hidden columns per k2 block
#define LHALF 256     // l-range per k3 block

#define TWO_PI_F 6.28318530717958647692f

__device__ __forceinline__ uint32_t rotl32(uint32_t x, int d){ return (x<<d)|(x>>(32-d)); }

__device__ __forceinline__ void tf_rounds4(uint32_t& x0, uint32_t& x1, int a, int b, int c, int d){
  x0+=x1; x1=rotl32(x1,a); x1^=x0;
  x0+=x1; x1=rotl32(x1,b); x1^=x0;
  x0+=x1; x1=rotl32(x1,c); x1^=x0;
  x0+=x1; x1=rotl32(x1,d); x1^=x0;
}

// Threefry-2x32, 20 rounds, matching jax._src.prng.threefry2x32
__device__ void threefry2x32(uint32_t k0, uint32_t k1, uint32_t x0, uint32_t x1,
                             uint32_t& o0, uint32_t& o1)
{
  const uint32_t ks2 = k0 ^ k1 ^ 0x1BD11BDAu;
  x0 += k0; x1 += k1;
  tf_rounds4(x0,x1,13,15,26,6);   x0+=k1;  x1+=ks2+1u;
  tf_rounds4(x0,x1,17,29,16,24);  x0+=ks2; x1+=k0+2u;
  tf_rounds4(x0,x1,13,15,26,6);   x0+=k0;  x1+=k1+3u;
  tf_rounds4(x0,x1,17,29,16,24);  x0+=k1;  x1+=ks2+4u;
  tf_rounds4(x0,x1,13,15,26,6);   x0+=ks2; x1+=k0+5u;
  o0 = x0; o1 = x1;
}

// Reproduces _ray_directions() for ray r (verified round 0: partitionable
// threefry, counter=(0,i), bits = out0 ^ out1).
__device__ void ray_dir(int r, float d[3])
{
  if (r >= 512) { d[0]=0.f; d[1]=0.f; d[2] = (r==512) ? 1.0f : -1.0f; return; }
  int i = r >> 4, j = r & 15;
  uint32_t o0, o1;
  threefry2x32(0u, 42u, 0u, (uint32_t)i, o0, o1);
  uint32_t bits = o0 ^ o1;
  float u = __uint_as_float((bits >> 9) | 0x3F800000u) - 1.0f;   // uniform [0,1)
  const float step = TWO_PI_F / 32.0f;
  float a = (float)i * step + step * u;
  float e = acosf(2.0f * ((float)(j+1) * (1.0f/17.0f)) - 1.0f);
  float se = sinf(e);
  d[0] = cosf(a) * se;
  d[1] = sinf(a) * se;
  d[2] = cosf(e);
}

__device__ __forceinline__ float dval(int s){ return ((float)s*(1.0f/63.0f))*7.9f + 0.1f; }

// K1: per-ray MLP + attention weights + tx-delay.
// Layout now (b, s, r, j) so k2 reads a contiguous slab per (b,s). wh in fp16.
__global__ __launch_bounds__(64)
void k1_rays(const float* __restrict__ rays_o, const float* __restrict__ position_tx,
             const float* __restrict__ W1, const float* __restrict__ b1,
             const float* __restrict__ w_attn,
             __half* __restrict__ wh, float* __restrict__ w_arr, int* __restrict__ delay_arr)
{
  const int br = blockIdx.x;
  const int b = br / RAYS, r = br % RAYS;
  const int lane = threadIdx.x;

  float dir[3]; ray_dir(r, dir);
  const float mn[3] = {-5.f,-5.f,-3.f}, mx[3] = {5.f,5.f,3.f};
  float ro[3], ntx[3];
  #pragma unroll
  for (int c=0;c<3;c++){
    ro[c] = rays_o[b*3+c];
    float t = position_tx[b*3+c];
    ntx[c] = 2.0f*(t - mn[c])/(mx[c]-mn[c]) - 1.0f;
  }
  float w1r[9];
  #pragma unroll
  for (int f=0; f<9; f++) w1r[f] = W1[f*HIDN + lane];
  const float b1r = b1[lane];
  const float war = w_attn[lane];

  float T = 1.0f;
  for (int s=0; s<NS; s++){
    float dv = dval(s);
    float npt[3], dd2 = 0.f;
    #pragma unroll
    for (int c=0;c<3;c++){
      float pt = ro[c] + dir[c]*dv;
      npt[c] = 2.0f*(pt - mn[c])/(mx[c]-mn[c]) - 1.0f;
      float ddc = ((ntx[c]-npt[c]) + 1.0f)/2.0f*(mx[c]-mn[c]) + mn[c];
      dd2 += ddc*ddc;
    }
    float h = b1r;
    h += npt[0]*w1r[0] + npt[1]*w1r[1] + npt[2]*w1r[2];
    h += (-dir[0])*w1r[3] + (-dir[1])*w1r[4] + (-dir[2])*w1r[5];
    h += ntx[0]*w1r[6] + ntx[1]*w1r[7] + ntx[2]*w1r[8];
    h = fmaxf(h, 0.0f);

    float av = h * war;
    #pragma unroll
    for (int m=32; m>=1; m>>=1) av += __shfl_xor(av, m, 64);

    float attn = fmaxf(av, 0.f) + log1pf(expf(-fabsf(av)));   // softplus
    float dist = (s < NS-1) ? (dval(s+1) - dv) : 1e10f;
    float alpha = 1.0f - expf(-attn*dist);
    float wgt = T * alpha;
    T = T * (1.0f - alpha + 1e-6f);

    float idxf = (sqrtf(dd2)*16000.0f)/343.0f;
    float delf = fminf(fmaxf(rintf(idxf), 0.f), 511.f);

    int o2 = (b*NS + s)*RAYS + r;
    wh[(size_t)o2*HIDN + lane] = __float2half(wgt * h);
    if (lane == 0){
      w_arr[o2] = wgt;
      delay_arr[o2] = (int)delf;
    }
  }
}

// K2: per (b,s,p): delay-bucket scatter of 16 columns of w*h (+ redundant w col),
// blocked parallel inclusive scan over delay, partial dot with W_sig chunk.
// Dpart[p][bs][l]; p==0 additionally carries the b_sig * Wsum_cum term.
__global__ __launch_bounds__(256)
void k2_bucket(const __half* __restrict__ wh, const float* __restrict__ w_arr,
               const int* __restrict__ delay_arr,
               const float* __restrict__ W_sig, const float* __restrict__ b_sig,
               float* __restrict__ Dpart)
{
  __shared__ float bucket[LSEQ][JC+1];   // col JC = w column; 512*17*4 = 34,816 B
  __shared__ float part[16][JC+1];
  const int blk = blockIdx.x;
  const int bsid = blk / SPLIT, p = blk % SPLIT;
  const int b = bsid / NS, s = bsid % NS;
  const int tid = threadIdx.x;
  const int j = tid & 15, slice = tid >> 4;   // 16 slices x 16 cols
  const int jbase = p*JC;
  const int obase = (b*NS + s)*RAYS;

  for (int i = tid; i < LSEQ*(JC+1); i += 256) (&bucket[0][0])[i] = 0.f;
  __syncthreads();

  // scatter (LDS float atomics are fire-and-forget)
  for (int r = slice; r < RAYS; r += 16){
    int o2 = obase + r;
    int d = delay_arr[o2];                       // broadcast across 16 j-lanes
    float v = __half2float(wh[(size_t)o2*HIDN + jbase + j]);
    atomicAdd(&bucket[d][j], v);
    if (j == 15) atomicAdd(&bucket[d][JC], w_arr[o2]);
  }
  __syncthreads();

  // blocked inclusive scan: 16 segs of 32 rows; thread (seg,j) scans column j,
  // j==15 threads additionally scan the w column.
  {
    const int seg = slice, d0 = seg*32;
    float run = 0.f;
    for (int k=0;k<32;k++){ run += bucket[d0+k][j]; bucket[d0+k][j] = run; }
    part[seg][j] = run;
    if (j == 15){
      float runw = 0.f;
      for (int k=0;k<32;k++){ runw += bucket[d0+k][JC]; bucket[d0+k][JC] = runw; }
      part[seg][JC] = runw;
    }
  }
  __syncthreads();
  {
    const int seg = slice, d0 = seg*32;
    float off = 0.f;
    for (int t=0;t<seg;t++) off += part[t][j];
    for (int k=0;k<32;k++) bucket[d0+k][j] += off;
    if (j == 15){
      float offw = 0.f;
      for (int t=0;t<seg;t++) offw += part[t][JC];
      for (int k=0;k<32;k++) bucket[d0+k][JC] += offw;
    }
  }
  __syncthreads();

  // partial dot: stride-17 rows -> bank = (17l+j)%32, conflict-free across l
  for (int l = tid; l < LSEQ; l += 256){
    float acc = 0.f;
    #pragma unroll
    for (int jj=0;jj<JC;jj++) acc += bucket[l][jj] * W_sig[(jbase+jj)*LSEQ + l];
    if (p == 0) acc += b_sig[l] * bucket[l][JC];
    Dpart[((size_t)p*BS*NS + bsid)*LSEQ + l] = acc;
  }
}

// K3: per (b,s,half): combine Dpart + masks + path loss into g (LDS), then
// 256-point partial direct DFT over this l-half for all 257 bins + frac phase.
__global__ __launch_bounds__(256)
void k3_dft(const float* __restrict__ Dpart, float* __restrict__ partial)
{
  __shared__ float gs[LHALF];
  __shared__ float2 tw[LSEQ];
  const int blk = blockIdx.x;
  const int bsid = blk >> 1, half = blk & 1;
  const int s = bsid % NS;
  const int tid = threadIdx.x;
  const int l0 = half*LHALF;

  for (int t = tid; t < LSEQ; t += 256){
    float sv, cv;
    sincosf(-(TWO_PI_F/512.0f)*(float)t, &sv, &cv);
    tw[t] = make_float2(cv, sv);
  }

  float dv = dval(s);
  float shiftf = rintf((16000.0f*dv)/343.0f);
  int shift = (int)shiftf;
  {
    int l = tid;           // LHALF == blockDim.x
    int lg = l0 + l;
    float acc = 0.f;
    #pragma unroll
    for (int p=0;p<SPLIT;p++) acc += Dpart[((size_t)p*BS*NS + bsid)*LSEQ + lg];
    float mt = (((float)(LSEQ-1-lg)) - shiftf > 0.f) ? 1.f : 0.f;
    int pli = shift + lg;
    if (pli < 4) pli = 5;                       // path_loss[:4] = path_loss[5]
    float ideal = ((float)pli/16000.0f)*343.0f;
    gs[l] = acc * mt / (ideal + 0.001f);
  }
  __syncthreads();

  float c = (16000.0f*dv)/343.0f;               // fractional pts2rx_idx
  for (int k = tid; k < NF; k += 256){
    float re = 0.f, im = 0.f;
    for (int l=0; l<LHALF; l++){
      int t = (k*(l0+l)) & (LSEQ-1);
      float2 w = tw[t];
      float gv = gs[l];
      re = fmaf(gv, w.x, re);
      im = fmaf(gv, w.y, im);
    }
    float ang = -(TWO_PI_F/512.0f)*((float)k*c);
    float sp, cp; sincosf(ang, &sp, &cp);
    float orr = re*cp - im*sp;
    float oi  = re*sp + im*cp;
    size_t o = (((size_t)bsid*2 + half)*NF + k)*2;
    partial[o]   = orr;
    partial[o+1] = oi;
  }
}

// K4: deterministic reduction over (s, half).
__global__ __launch_bounds__(256)
void k4_reduce(const float* __restrict__ partial, float* __restrict__ out)
{
  int idx = blockIdx.x*256 + threadIdx.x;
  if (idx >= BS*NF*2) return;
  int b = idx / (NF*2);
  int rem = idx - b*(NF*2);
  int k = rem >> 1, comp = rem & 1;
  float acc = 0.f;
  for (int sh=0; sh<NS*2; sh++)
    acc += partial[((size_t)(b*NS*2 + sh)*NF + k)*2 + comp];
  out[(b*NF + k)*2 + comp] = acc;
}

extern "C" void kernel_launch(void* const* d_in, const int* in_sizes, int n_in,
                              void* d_out, int out_size, void* d_ws, size_t ws_size,
                              hipStream_t stream)
{
  const float* rays_o      = (const float*)d_in[0];
  const float* position_tx = (const float*)d_in[1];
  const float* W1          = (const float*)d_in[2];
  const float* b1          = (const float*)d_in[3];
  const float* w_attn      = (const float*)d_in[4];
  const float* W_sig       = (const float*)d_in[5];
  const float* b_sig       = (const float*)d_in[6];
  float* out = (float*)d_out;

  // workspace layout (~10.0 MB total)
  char* ws = (char*)d_ws;
  __half* wh       = (__half*)ws;                               // 2*64*514*64*2B = 8,421,376
  float* w_arr     = (float*)(ws + 8421376);                    // 263,168
  int*   delay_arr = (int*)  (ws + 8421376 + 263168);           // 263,168
  float* Dpart     = (float*)(ws + 8421376 + 2*263168);         // 4*128*512*4 = 1,048,576
  float* partial   = (float*)(ws + 8421376 + 2*263168 + 1048576); // 526,336

  k1_rays  <<<BS*RAYS,           64, 0, stream>>>(rays_o, position_tx, W1, b1, w_attn,
                                                  wh, w_arr, delay_arr);
  k2_bucket<<<BS*NS*SPLIT,      256, 0, stream>>>(wh, w_arr, delay_arr, W_sig, b_sig, Dpart);
  k3_dft   <<<BS*NS*2,          256, 0, stream>>>(Dpart, partial);
  k4_reduce<<<(BS*NF*2+255)/256,256, 0, stream>>>(partial, out);
}

// Round 3
// 77.281 us; speedup vs baseline: 3.3337x; 1.6247x over previous
//
#include <hip/hip_runtime.h>
#include <hip/hip_fp16.h>
#include <stdint.h>
#include <math.h>

#define BS    2
#define RAYS  514
#define NS    64
#define LSEQ  512
#define NF    257
#define HIDN  64
#define SPLIT 4
#define JC    16      // hidden columns per k2 block
#define LQ    128     // l-range per k3 block (quarter)

#define TWO_PI_F 6.28318530717958647692f

__device__ __forceinline__ uint32_t rotl32(uint32_t x, int d){ return (x<<d)|(x>>(32-d)); }

__device__ __forceinline__ void tf_rounds4(uint32_t& x0, uint32_t& x1, int a, int b, int c, int d){
  x0+=x1; x1=rotl32(x1,a); x1^=x0;
  x0+=x1; x1=rotl32(x1,b); x1^=x0;
  x0+=x1; x1=rotl32(x1,c); x1^=x0;
  x0+=x1; x1=rotl32(x1,d); x1^=x0;
}

// Threefry-2x32, 20 rounds, matching jax._src.prng.threefry2x32
__device__ void threefry2x32(uint32_t k0, uint32_t k1, uint32_t x0, uint32_t x1,
                             uint32_t& o0, uint32_t& o1)
{
  const uint32_t ks2 = k0 ^ k1 ^ 0x1BD11BDAu;
  x0 += k0; x1 += k1;
  tf_rounds4(x0,x1,13,15,26,6);   x0+=k1;  x1+=ks2+1u;
  tf_rounds4(x0,x1,17,29,16,24);  x0+=ks2; x1+=k0+2u;
  tf_rounds4(x0,x1,13,15,26,6);   x0+=k0;  x1+=k1+3u;
  tf_rounds4(x0,x1,17,29,16,24);  x0+=k1;  x1+=ks2+4u;
  tf_rounds4(x0,x1,13,15,26,6);   x0+=ks2; x1+=k0+5u;
  o0 = x0; o1 = x1;
}

// Reproduces _ray_directions() for ray r (verified round 0: partitionable
// threefry, counter=(0,i), bits = out0 ^ out1).
__device__ void ray_dir(int r, float d[3])
{
  if (r >= 512) { d[0]=0.f; d[1]=0.f; d[2] = (r==512) ? 1.0f : -1.0f; return; }
  int i = r >> 4, j = r & 15;
  uint32_t o0, o1;
  threefry2x32(0u, 42u, 0u, (uint32_t)i, o0, o1);
  uint32_t bits = o0 ^ o1;
  float u = __uint_as_float((bits >> 9) | 0x3F800000u) - 1.0f;   // uniform [0,1)
  const float step = TWO_PI_F / 32.0f;
  float a = (float)i * step + step * u;
  float e = acosf(2.0f * ((float)(j+1) * (1.0f/17.0f)) - 1.0f);
  float se = sinf(e);
  d[0] = cosf(a) * se;
  d[1] = sinf(a) * se;
  d[2] = cosf(e);
}

__device__ __forceinline__ float dval(int s){ return ((float)s*(1.0f/63.0f))*7.9f + 0.1f; }

__device__ __forceinline__ uint32_t pk2(float a, float b){
  return (uint32_t)__half_as_ushort(__float2half(a)) |
         ((uint32_t)__half_as_ushort(__float2half(b)) << 16);
}

// K1 (restructured): lane = s. Each lane computes its sample's full hidden
// vector h[64] (independent dense FMA, weights via scalar loads), attn,
// and the transmittance via ONE wave-wide multiplicative scan.
__global__ __launch_bounds__(64)
void k1_rays(const float* __restrict__ rays_o, const float* __restrict__ position_tx,
             const float* __restrict__ W1, const float* __restrict__ b1,
             const float* __restrict__ w_attn,
             __half* __restrict__ wh, float* __restrict__ w_arr, int* __restrict__ delay_arr)
{
  const int br = blockIdx.x;
  const int b = br / RAYS, r = br % RAYS;
  const int lane = threadIdx.x;      // s index

  float dir[3]; ray_dir(r, dir);
  const float mn[3] = {-5.f,-5.f,-3.f}, mx[3] = {5.f,5.f,3.f};
  float ro[3], ntx[3];
  #pragma unroll
  for (int c=0;c<3;c++){
    ro[c] = rays_o[b*3+c];
    float t = position_tx[b*3+c];
    ntx[c] = 2.0f*(t - mn[c])/(mx[c]-mn[c]) - 1.0f;
  }

  const float dv = dval(lane);
  float feat[9], dd2 = 0.f;
  #pragma unroll
  for (int c=0;c<3;c++){
    float pt = ro[c] + dir[c]*dv;
    float npt = 2.0f*(pt - mn[c])/(mx[c]-mn[c]) - 1.0f;
    float ddc = ((ntx[c]-npt) + 1.0f)/2.0f*(mx[c]-mn[c]) + mn[c];
    dd2 += ddc*ddc;
    feat[c]   = npt;
    feat[3+c] = -dir[c];
    feat[6+c] = ntx[c];
  }

  float h[HIDN];
  float av = 0.f;
  #pragma unroll
  for (int j=0; j<HIDN; j++){
    float hj = b1[j];
    #pragma unroll
    for (int f=0; f<9; f++) hj = fmaf(feat[f], W1[f*HIDN + j], hj);
    hj = fmaxf(hj, 0.0f);
    h[j] = hj;
    av = fmaf(hj, w_attn[j], av);
  }

  float attn = fmaxf(av, 0.f) + log1pf(expf(-fabsf(av)));   // softplus
  float dist = (lane < NS-1) ? (dval(lane+1) - dv) : 1e10f;
  float alpha = 1.0f - expf(-attn*dist);

  // inclusive multiplicative scan of f = 1-alpha+1e-6 over lanes, then shift
  float fac = 1.0f - alpha + 1e-6f;
  float scan = fac;
  #pragma unroll
  for (int m=1; m<64; m<<=1){
    float up = __shfl_up(scan, m, 64);
    if (lane >= m) scan *= up;
  }
  float T = __shfl_up(scan, 1, 64);
  if (lane == 0) T = 1.0f;
  float wgt = T * alpha;

  float delf = fminf(fmaxf(rintf(sqrtf(dd2)*16000.0f/343.0f), 0.f), 511.f);

  const int o2 = (b*NS + lane)*RAYS + r;
  w_arr[o2] = wgt;
  delay_arr[o2] = (int)delf;

  // each lane writes its own contiguous 128-B wh row (layout (b,s,r,j))
  uint4* dst = (uint4*)(wh + (size_t)o2*HIDN);
  #pragma unroll
  for (int q=0; q<8; q++){
    uint4 v;
    v.x = pk2(wgt*h[q*8+0], wgt*h[q*8+1]);
    v.y = pk2(wgt*h[q*8+2], wgt*h[q*8+3]);
    v.z = pk2(wgt*h[q*8+4], wgt*h[q*8+5]);
    v.w = pk2(wgt*h[q*8+6], wgt*h[q*8+7]);
    dst[q] = v;
  }
}

// K2: per (b,s,p): delay-bucket scatter of 16 columns of w*h (+ redundant w col),
// blocked parallel inclusive scan over delay, partial dot with W_sig chunk.
// Dpart[p][bs][l]; p==0 additionally carries the b_sig * Wsum_cum term.
__global__ __launch_bounds__(256)
void k2_bucket(const __half* __restrict__ wh, const float* __restrict__ w_arr,
               const int* __restrict__ delay_arr,
               const float* __restrict__ W_sig, const float* __restrict__ b_sig,
               float* __restrict__ Dpart)
{
  __shared__ float bucket[LSEQ][JC+1];   // col JC = w column; 512*17*4 = 34,816 B
  __shared__ float part[16][JC+1];
  const int blk = blockIdx.x;
  const int bsid = blk / SPLIT, p = blk % SPLIT;
  const int b = bsid / NS, s = bsid % NS;
  const int tid = threadIdx.x;
  const int j = tid & 15, slice = tid >> 4;   // 16 slices x 16 cols
  const int jbase = p*JC;
  const int obase = (b*NS + s)*RAYS;

  for (int i = tid; i < LSEQ*(JC+1); i += 256) (&bucket[0][0])[i] = 0.f;
  __syncthreads();

  // scatter (LDS float atomics are fire-and-forget)
  for (int r = slice; r < RAYS; r += 16){
    int o2 = obase + r;
    int d = delay_arr[o2];                       // broadcast across 16 j-lanes
    float v = __half2float(wh[(size_t)o2*HIDN + jbase + j]);
    atomicAdd(&bucket[d][j], v);
    if (j == 15) atomicAdd(&bucket[d][JC], w_arr[o2]);
  }
  __syncthreads();

  // blocked inclusive scan: 16 segs of 32 rows
  {
    const int seg = slice, d0 = seg*32;
    float run = 0.f;
    for (int k=0;k<32;k++){ run += bucket[d0+k][j]; bucket[d0+k][j] = run; }
    part[seg][j] = run;
    if (j == 15){
      float runw = 0.f;
      for (int k=0;k<32;k++){ runw += bucket[d0+k][JC]; bucket[d0+k][JC] = runw; }
      part[seg][JC] = runw;
    }
  }
  __syncthreads();
  {
    const int seg = slice, d0 = seg*32;
    float off = 0.f;
    for (int t=0;t<seg;t++) off += part[t][j];
    for (int k=0;k<32;k++) bucket[d0+k][j] += off;
    if (j == 15){
      float offw = 0.f;
      for (int t=0;t<seg;t++) offw += part[t][JC];
      for (int k=0;k<32;k++) bucket[d0+k][JC] += offw;
    }
  }
  __syncthreads();

  // partial dot: stride-17 rows -> conflict-free across l
  for (int l = tid; l < LSEQ; l += 256){
    float acc = 0.f;
    #pragma unroll
    for (int jj=0;jj<JC;jj++) acc += bucket[l][jj] * W_sig[(jbase+jj)*LSEQ + l];
    if (p == 0) acc += b_sig[l] * bucket[l][JC];
    Dpart[((size_t)p*BS*NS + bsid)*LSEQ + l] = acc;
  }
}

// K3: per (b,s,quarter): combine Dpart + masks + path loss into g (LDS), then
// 128-point partial direct DFT over this l-quarter for all 257 bins + frac phase.
__global__ __launch_bounds__(256)
void k3_dft(const float* __restrict__ Dpart, float* __restrict__ partial)
{
  __shared__ float gs[LQ];
  __shared__ float2 tw[LSEQ];
  const int blk = blockIdx.x;
  const int bsid = blk >> 2, quarter = blk & 3;
  const int s = bsid % NS;
  const int tid = threadIdx.x;
  const int l0 = quarter*LQ;

  for (int t = tid; t < LSEQ; t += 256){
    float sv, cv;
    sincosf(-(TWO_PI_F/512.0f)*(float)t, &sv, &cv);
    tw[t] = make_float2(cv, sv);
  }

  float dv = dval(s);
  float shiftf = rintf((16000.0f*dv)/343.0f);
  int shift = (int)shiftf;
  if (tid < LQ){
    int lg = l0 + tid;
    float acc = 0.f;
    #pragma unroll
    for (int p=0;p<SPLIT;p++) acc += Dpart[((size_t)p*BS*NS + bsid)*LSEQ + lg];
    float mt = (((float)(LSEQ-1-lg)) - shiftf > 0.f) ? 1.f : 0.f;
    int pli = shift + lg;
    if (pli < 4) pli = 5;                       // path_loss[:4] = path_loss[5]
    float ideal = ((float)pli/16000.0f)*343.0f;
    gs[tid] = acc * mt / (ideal + 0.001f);
  }
  __syncthreads();

  float c = (16000.0f*dv)/343.0f;               // fractional pts2rx_idx
  for (int k = tid; k < NF; k += 256){
    float re = 0.f, im = 0.f;
    for (int l=0; l<LQ; l++){
      int t = (k*(l0+l)) & (LSEQ-1);
      float2 w = tw[t];
      float gv = gs[l];
      re = fmaf(gv, w.x, re);
      im = fmaf(gv, w.y, im);
    }
    float ang = -(TWO_PI_F/512.0f)*((float)k*c);
    float sp, cp; sincosf(ang, &sp, &cp);
    float orr = re*cp - im*sp;
    float oi  = re*sp + im*cp;
    size_t o = (((size_t)bsid*4 + quarter)*NF + k)*2;
    partial[o]   = orr;
    partial[o+1] = oi;
  }
}

// K4: deterministic reduction over (s, quarter): 4-way split + LDS combine.
__global__ __launch_bounds__(256)
void k4_reduce(const float* __restrict__ partial, float* __restrict__ out)
{
  __shared__ float red[4][64];
  const int tid = threadIdx.x;
  const int ol = tid & 63, chunk = tid >> 6;
  const int o = blockIdx.x*64 + ol;
  float acc = 0.f;
  if (o < BS*NF*2){
    int b = o / (NF*2);
    int rem = o - b*(NF*2);
    int k = rem >> 1, comp = rem & 1;
    for (int sh=chunk; sh<NS*4; sh+=4)
      acc += partial[((size_t)(b*NS*4 + sh)*NF + k)*2 + comp];
  }
  red[chunk][ol] = acc;
  __syncthreads();
  if (tid < 64 && o < BS*NF*2){
    int b = o / (NF*2);
    int rem = o - b*(NF*2);
    int k = rem >> 1, comp = rem & 1;
    out[(b*NF + k)*2 + comp] = red[0][ol]+red[1][ol]+red[2][ol]+red[3][ol];
  }
}

extern "C" void kernel_launch(void* const* d_in, const int* in_sizes, int n_in,
                              void* d_out, int out_size, void* d_ws, size_t ws_size,
                              hipStream_t stream)
{
  const float* rays_o      = (const float*)d_in[0];
  const float* position_tx = (const float*)d_in[1];
  const float* W1          = (const float*)d_in[2];
  const float* b1          = (const float*)d_in[3];
  const float* w_attn      = (const float*)d_in[4];
  const float* W_sig       = (const float*)d_in[5];
  const float* b_sig       = (const float*)d_in[6];
  float* out = (float*)d_out;

  // workspace layout (~12.1 MB total)
  char* ws = (char*)d_ws;
  __half* wh       = (__half*)ws;                               // 2*64*514*64*2B = 8,421,376
  float* w_arr     = (float*)(ws + 8421376);                    // 263,168
  int*   delay_arr = (int*)  (ws + 8421376 + 263168);           // 263,168
  float* Dpart     = (float*)(ws + 8421376 + 2*263168);         // 4*128*512*4 = 1,048,576
  float* partial   = (float*)(ws + 8421376 + 2*263168 + 1048576); // 2*256*257*2*4 = 2,105,344

  k1_rays  <<<BS*RAYS,            64, 0, stream>>>(rays_o, position_tx, W1, b1, w_attn,
                                                   wh, w_arr, delay_arr);
  k2_bucket<<<BS*NS*SPLIT,       256, 0, stream>>>(wh, w_arr, delay_arr, W_sig, b_sig, Dpart);
  k3_dft   <<<BS*NS*4,           256, 0, stream>>>(Dpart, partial);
  k4_reduce<<<(BS*NF*2+63)/64,   256, 0, stream>>>(partial, out);
}